// Round 1
// baseline (156.388 us; speedup 1.0000x reference)
//
#include <hip/hip_runtime.h>
#include <hip/hip_bf16.h>

typedef __bf16 bf16_t;
typedef __attribute__((ext_vector_type(4))) float f32x4;
typedef __attribute__((ext_vector_type(8))) __bf16 bf16x8;
typedef __attribute__((ext_vector_type(4))) __bf16 bf16x4;
typedef __attribute__((ext_vector_type(2))) __bf16 bf16x2;

#define NQ    1024
#define DIM   384
#define NHEAD 8
#define HDIM  48
#define HALFD 24
#define NLVL  4
#define NSZ   7
#define NKEY  196
#define NFREQ 8

// ---------------------------------------------------------------------------
// Generic NT GEMM: C[M,N] = A[M,K] * B[N,K]^T   (A,B fp32 in; bf16 MFMA)
// EPI: 0 = fp32 C, 1 = fp32 C + residual, 2 = bf16 C
// Tiles: 128x128, BK=32, 4 waves each computing a 64x64 sub-tile (4x4 frags).
// ---------------------------------------------------------------------------
template<int EPI>
__global__ __launch_bounds__(256) void gemm_nt(
    const float* __restrict__ A, const float* __restrict__ Bw,
    void* __restrict__ Cp, const float* __restrict__ resid,
    int M, int Nout, int K)
{
    __shared__ bf16_t As[128][40];   // +8 bf16 pad -> 80B row stride (2-way banks, free)
    __shared__ bf16_t Bs[128][40];
    const int tid  = threadIdx.x;
    const int bm   = blockIdx.y, bn = blockIdx.x;
    const int wave = tid >> 6, lane = tid & 63;
    const int wr   = wave >> 1, wc = wave & 1;
    const int fr   = lane & 15, fk = (lane >> 4) << 3;

    f32x4 acc[4][4];
#pragma unroll
    for (int i = 0; i < 4; ++i)
#pragma unroll
        for (int j = 0; j < 4; ++j) acc[i][j] = (f32x4){0.f, 0.f, 0.f, 0.f};

    const float* Ab = A  + (size_t)bm * 128 * K;
    const float* Bb = Bw + (size_t)bn * 128 * K;

    for (int kt = 0; kt < K; kt += 32) {
        __syncthreads();
#pragma unroll
        for (int i = 0; i < 4; ++i) {
            int idx = tid + i * 256;
            int r = idx >> 3, c4 = (idx & 7) << 2;
            float4 va = *(const float4*)(Ab + (size_t)r * K + kt + c4);
            bf16x4 pa = { (bf16_t)va.x, (bf16_t)va.y, (bf16_t)va.z, (bf16_t)va.w };
            *(bf16x4*)(&As[r][c4]) = pa;
            float4 vb = *(const float4*)(Bb + (size_t)r * K + kt + c4);
            bf16x4 pb = { (bf16_t)vb.x, (bf16_t)vb.y, (bf16_t)vb.z, (bf16_t)vb.w };
            *(bf16x4*)(&Bs[r][c4]) = pb;
        }
        __syncthreads();
        bf16x8 af[4], bfr[4];
#pragma unroll
        for (int mi = 0; mi < 4; ++mi)
            af[mi] = *(const bf16x8*)(&As[wr * 64 + mi * 16 + fr][fk]);
#pragma unroll
        for (int ni = 0; ni < 4; ++ni)
            bfr[ni] = *(const bf16x8*)(&Bs[wc * 64 + ni * 16 + fr][fk]);
#pragma unroll
        for (int mi = 0; mi < 4; ++mi)
#pragma unroll
            for (int ni = 0; ni < 4; ++ni)
                acc[mi][ni] = __builtin_amdgcn_mfma_f32_16x16x32_bf16(
                    af[mi], bfr[ni], acc[mi][ni], 0, 0, 0);
    }

    const int r0 = (lane >> 4) << 2;
#pragma unroll
    for (int mi = 0; mi < 4; ++mi) {
#pragma unroll
        for (int ni = 0; ni < 4; ++ni) {
#pragma unroll
            for (int e = 0; e < 4; ++e) {
                int row = bm * 128 + wr * 64 + mi * 16 + r0 + e;
                int col = bn * 128 + wc * 64 + ni * 16 + fr;
                float v = acc[mi][ni][e];
                if (EPI == 2) {
                    ((bf16_t*)Cp)[(size_t)row * Nout + col] = (bf16_t)v;
                } else {
                    if (EPI == 1) v += resid[(size_t)row * Nout + col];
                    ((float*)Cp)[(size_t)row * Nout + col] = v;
                }
            }
        }
    }
}

// ---------------------------------------------------------------------------
// LayerNorm: one wave per row of 384
// ---------------------------------------------------------------------------
__global__ __launch_bounds__(64) void ln_kernel(
    const float* __restrict__ q, const float* __restrict__ w,
    const float* __restrict__ b, float* __restrict__ xout)
{
    const int n = blockIdx.x, lane = threadIdx.x;
    const float* row = q + (size_t)n * DIM;
    float v[6], s = 0.f, s2 = 0.f;
#pragma unroll
    for (int i = 0; i < 6; ++i) {
        v[i] = row[lane + i * 64];
        s += v[i]; s2 += v[i] * v[i];
    }
#pragma unroll
    for (int m = 32; m; m >>= 1) { s += __shfl_xor(s, m); s2 += __shfl_xor(s2, m); }
    float mu  = s * (1.f / DIM);
    float var = s2 * (1.f / DIM) - mu * mu;
    float rs  = rsqrtf(var + 1e-5f);
#pragma unroll
    for (int i = 0; i < 6; ++i) {
        int d = lane + i * 64;
        xout[(size_t)n * DIM + d] = (v[i] - mu) * rs * w[d] + b[d];
    }
}

// ---------------------------------------------------------------------------
// Attention: one block (256 threads) per query
// ---------------------------------------------------------------------------
__global__ __launch_bounds__(256) void attn_kernel(
    const float* __restrict__ qproj,   // (N,384) pre-RoPE
    const int*   __restrict__ pos,     // (N,4) b,i,j,l
    const bf16_t* __restrict__ kvm,    // (B*total, 768) bf16
    const int*   __restrict__ shapes,  // (L,2)
    float* __restrict__ attn_out)      // (N,384)
{
    __shared__ float qs[DIM];
    __shared__ float csnC[NKEY][HALFD];
    __shared__ float csnS[NKEY][HALFD];
    __shared__ float sc[NHEAD * NKEY];
    __shared__ int   flatL[NKEY], validL[NKEY], kiL[NKEY], kjL[NKEY];
    __shared__ int   shHs[NLVL], shWs[NLVL], shOffs[NLVL], shTot;
    __shared__ float fsL[NFREQ], flL[NFREQ];

    const int n = blockIdx.x, tid = threadIdx.x;

    if (tid == 0) {
        int o = 0;
        for (int l = 0; l < NLVL; ++l) {
            shHs[l] = shapes[2 * l]; shWs[l] = shapes[2 * l + 1];
            shOffs[l] = o; o += shapes[2 * l] * shapes[2 * l + 1];
        }
        shTot = o;
    }
    if (tid < NFREQ) {
        fsL[tid] = powf(10.0f, -(float)tid / (float)NFREQ);
        flL[tid] = powf(0.1f,  -(float)tid / (float)NFREQ);
    }
    const int b  = pos[n * 4 + 0];
    const int qi = pos[n * 4 + 1];
    const int qj = pos[n * 4 + 2];
    const int ql = pos[n * 4 + 3];
    __syncthreads();

    const float Hq = (float)shHs[ql], Wq = (float)shWs[ql];

    // q RoPE -> qs
    if (tid < NHEAD * HALFD) {
        int h = tid / HALFD, d = tid - h * HALFD;
        float coord, freq;
        if (d < 8)       { coord = (float)qi; freq = fsL[d]; }
        else if (d < 16) { coord = (float)qj; freq = fsL[d - 8]; }
        else             { coord = (float)ql; freq = flL[d - 16]; }
        float s, c; sincosf(coord * freq, &s, &c);
        float x1 = qproj[(size_t)n * DIM + h * HDIM + d];
        float x2 = qproj[(size_t)n * DIM + h * HDIM + HALFD + d];
        qs[h * HDIM + d]         = x1 * c - x2 * s;
        qs[h * HDIM + HALFD + d] = x1 * s + x2 * c;
    }

    // per-key geometry
    for (int kk = tid; kk < NKEY; kk += 256) {
        int l = kk / 49;
        int rem = kk - l * 49;
        int a = rem / 7, bb = rem - a * 7;
        int Hl = shHs[l], Wl = shWs[l];
        float cif = floorf(((float)qi + 0.5f) * (float)Hl / Hq);
        float cjf = floorf(((float)qj + 0.5f) * (float)Wl / Wq);
        int ii = (int)cif + (a - 3);
        int jj = (int)cjf + (bb - 3);
        int vi = (ii >= 0) && (ii < Hl);
        int vj = (jj >= 0) && (jj < Wl);
        int iic = min(max(ii, 0), Hl - 1);
        int jjc = min(max(jj, 0), Wl - 1);
        flatL[kk]  = shOffs[l] + iic * Wl + jjc;
        validL[kk] = vi && vj;
        kiL[kk] = iic; kjL[kk] = jjc;
    }
    __syncthreads();

    // key RoPE tables
    for (int task = tid; task < NKEY * HALFD; task += 256) {
        int kk = task / HALFD, f = task - kk * HALFD;
        int l = kk / 49;
        float coord, freq;
        if (f < 8)       { coord = (float)kiL[kk]; freq = fsL[f]; }
        else if (f < 16) { coord = (float)kjL[kk]; freq = fsL[f - 8]; }
        else             { coord = (float)l;       freq = flL[f - 16]; }
        float s, c; sincosf(coord * freq, &s, &c);
        csnC[kk][f] = c; csnS[kk][f] = s;
    }
    __syncthreads();

    const size_t bbase = (size_t)b * (size_t)shTot;

    // scores: 8 heads x 196 keys
    for (int idx = tid; idx < NHEAD * NKEY; idx += 256) {
        int h = idx / NKEY, kk = idx - h * NKEY;
        const bf16_t* krow = kvm + ((bbase + (size_t)flatL[kk]) * (2 * DIM)) + h * HDIM;
        bf16x8 kv[6];
#pragma unroll
        for (int i = 0; i < 6; ++i) kv[i] = *(const bf16x8*)(krow + i * 8);
        float dot = 0.f;
#pragma unroll
        for (int d = 0; d < HALFD; ++d) {
            float k1 = (float)kv[d >> 3][d & 7];
            float k2 = (float)kv[3 + (d >> 3)][d & 7];
            float c = csnC[kk][d], s = csnS[kk][d];
            dot += (k1 * c - k2 * s) * qs[h * HDIM + d]
                 + (k1 * s + k2 * c) * qs[h * HDIM + HALFD + d];
        }
        float score = dot * 0.14433756729740643f;  // 1/sqrt(48)
        if (!validL[kk]) score = -1e9f;
        sc[h * NKEY + kk] = score;
    }
    __syncthreads();

    // softmax: head h by threads [h*32, h*32+32)
    {
        int h = tid >> 5, lg = tid & 31;
        float mx = -1e30f;
        for (int j = lg; j < NKEY; j += 32) mx = fmaxf(mx, sc[h * NKEY + j]);
#pragma unroll
        for (int m = 16; m; m >>= 1) mx = fmaxf(mx, __shfl_xor(mx, m));
        float sum = 0.f;
        for (int j = lg; j < NKEY; j += 32) {
            float e = __expf(sc[h * NKEY + j] - mx);
            sc[h * NKEY + j] = e; sum += e;
        }
#pragma unroll
        for (int m = 16; m; m >>= 1) sum += __shfl_xor(sum, m);
        float inv = 1.f / sum;
        for (int j = lg; j < NKEY; j += 32) sc[h * NKEY + j] *= inv;
    }
    __syncthreads();

    // V accumulation: 192 threads x 2 dims
    if (tid < 192) {
        int h = tid / 24;
        float a0 = 0.f, a1 = 0.f;
#pragma unroll 4
        for (int kk = 0; kk < NKEY; ++kk) {
            float w = sc[h * NKEY + kk];
            const bf16_t* vr = kvm + (bbase + (size_t)flatL[kk]) * (2 * DIM) + DIM + 2 * tid;
            bf16x2 vv = *(const bf16x2*)vr;
            a0 += w * (float)vv[0];
            a1 += w * (float)vv[1];
        }
        attn_out[(size_t)n * DIM + 2 * tid]     = a0;
        attn_out[(size_t)n * DIM + 2 * tid + 1] = a1;
    }
}

// ---------------------------------------------------------------------------
extern "C" void kernel_launch(void* const* d_in, const int* in_sizes, int n_in,
                              void* d_out, int out_size, void* d_ws, size_t ws_size,
                              hipStream_t stream)
{
    const float* query  = (const float*)d_in[0];
    const int*   pos    = (const int*)d_in[1];
    const float* fmaps  = (const float*)d_in[3];
    const int*   shapes = (const int*)d_in[4];
    const float* nw     = (const float*)d_in[5];
    const float* nb     = (const float*)d_in[6];
    const float* wq     = (const float*)d_in[7];
    const float* wkv    = (const float*)d_in[8];
    const float* wout   = (const float*)d_in[9];
    float* out = (float*)d_out;

    const int Mkv = in_sizes[3] / DIM;  // B*total = 21760

    char* w = (char*)d_ws;
    float* x_ln   = (float*)w;  w += ((size_t)NQ * DIM * 4 + 255) / 256 * 256;
    float* qproj  = (float*)w;  w += ((size_t)NQ * DIM * 4 + 255) / 256 * 256;
    float* attn_o = (float*)w;  w += ((size_t)NQ * DIM * 4 + 255) / 256 * 256;
    bf16_t* kvm   = (bf16_t*)w; // Mkv * 768 * 2 bytes

    ln_kernel<<<NQ, 64, 0, stream>>>(query, nw, nb, x_ln);
    gemm_nt<2><<<dim3((2 * DIM) / 128, Mkv / 128), 256, 0, stream>>>(
        fmaps, wkv, (void*)kvm, nullptr, Mkv, 2 * DIM, DIM);
    gemm_nt<0><<<dim3(DIM / 128, NQ / 128), 256, 0, stream>>>(
        x_ln, wq, (void*)qproj, nullptr, NQ, DIM, DIM);
    attn_kernel<<<NQ, 256, 0, stream>>>(qproj, pos, kvm, shapes, attn_o);
    gemm_nt<1><<<dim3(DIM / 128, NQ / 128), 256, 0, stream>>>(
        attn_o, wout, (void*)out, query, NQ, DIM, DIM);
}